// Round 6
// baseline (1133.749 us; speedup 1.0000x reference)
//
#include <hip/hip_runtime.h>
#include <hip/hip_bf16.h>
#include <stdint.h>

// Binarized MLP: B=8192, D_IN=3072, H=2000 (pad 2048), C=10.
// L1 (exact, bf16 MFMA): Q=round(x*2^14)=d1*512+d0 digits exact in bf16.
// R11: fuse L1a+L1b into ONE GEMM with a SHARED B-tile. Key insight from R10
// counters: L1a at 40% MfmaUtil / 16% VALU / 44% BW is LDS+drain bound, and
// L1a's B ([s|s] dup) == L1b's B == s. Merged kernel stages {hi, lo, re, s}
// tiles (4 x 8 KiB, BK=32) and does 48 MFMA per barrier-pair sharing one fb:
//   accI += hi@s + lo@s (exact ints, order-free); accR += re@s (same MFMA
//   order as old L1b -> bit-identical); epilogue (double)accI+(double)accR
//   is exact => p0/habs BIT-IDENTICAL to the R6-verified path.
// Wins: -33% LDS fragment traffic, -128 MiB Ti round-trip, -1 node, sW1 dedup.
// VGPR ~195 (128 acc) => plain __launch_bounds__(256): do NOT force (256,4),
// that recreates the R7 spill (compiler would cap at 128 and spill acc).
// Layers 2-4: i8 MFMA on {0,1}x{+-1} — exact i32, BK=128. h4 in bf16.
typedef __bf16 bf16_t;
typedef __attribute__((ext_vector_type(8))) __bf16 bf16x8;
typedef __attribute__((ext_vector_type(4))) float f32x4;
typedef __attribute__((ext_vector_type(4))) int i32x4;
typedef __attribute__((ext_vector_type(8))) char i8x8;

#define GLD_LDS16(g, l) __builtin_amdgcn_global_load_lds( \
    (__attribute__((address_space(1))) void*)(g), \
    (__attribute__((address_space(3))) void*)(l), 16, 0, 0)

__device__ __forceinline__ void block_reduce_atomic_d(double v, double* dst) {
    #pragma unroll
    for (int off = 32; off > 0; off >>= 1) v += __shfl_down(v, off);
    __shared__ double rb[4];
    const int t = threadIdx.x;
    if ((t & 63) == 0) rb[t >> 6] = v;
    __syncthreads();
    if (t == 0) atomicAdd(dst, rb[0] + rb[1] + rb[2] + rb[3]);
}

// --- fused prep: one dispatch, 16384 blocks ---
// R11: sW1 is now SINGLE-copy [2048][3072] (the merged GEMM reads it once).
__device__ __forceinline__ void prep_w1_row(
    const float* __restrict__ W, int r, bf16_t* __restrict__ S, double* sumOut)
{
    const int t = threadIdx.x;
    double sl = 0.0;
    for (int cb = t * 8; cb < 3072; cb += 2048) {
        bf16x8 o;
        if (r < 2000) {
            #pragma unroll
            for (int j = 0; j < 8; ++j) {
                float v = W[(size_t)r * 3072 + cb + j];
                sl += (double)fabsf(v);
                o[j] = (bf16_t)(v > 0.f ? 1.f : (v < 0.f ? -1.f : 0.f));
            }
        } else {
            #pragma unroll
            for (int j = 0; j < 8; ++j) o[j] = (bf16_t)0.f;
        }
        *(bf16x8*)&S[(size_t)r * 3072 + cb] = o;
    }
    block_reduce_atomic_d(sl, sumOut);
}

__device__ __forceinline__ void prep_wi8_row(
    const float* __restrict__ W, int r, int8_t* __restrict__ S, double* sumOut)
{
    const int t = threadIdx.x;
    const int cb = t * 8;
    double sl = 0.0;
    i8x8 o;
    if (r < 2000) {
        #pragma unroll
        for (int j = 0; j < 8; ++j) {
            int c = cb + j;
            float v = (c < 2000) ? W[(size_t)r * 2000 + c] : 0.f;
            sl += (double)fabsf(v);
            o[j] = (char)(v > 0.f ? 1 : (v < 0.f ? -1 : 0));
        }
    } else {
        #pragma unroll
        for (int j = 0; j < 8; ++j) o[j] = 0;
    }
    *(i8x8*)&S[(size_t)r * 2048 + cb] = o;
    block_reduce_atomic_d(sl, sumOut);
}

__device__ __forceinline__ void prep_x_row(
    const float* __restrict__ x, int r, bf16_t* __restrict__ XLi, bf16_t* __restrict__ XLr)
{
    const int t = threadIdx.x;
    for (int cb = t * 8; cb < 3072; cb += 2048) {
        float4 v0 = *(const float4*)&x[(size_t)r * 3072 + cb];
        float4 v1 = *(const float4*)&x[(size_t)r * 3072 + cb + 4];
        float xv[8] = {v0.x, v0.y, v0.z, v0.w, v1.x, v1.y, v1.z, v1.w};
        bf16x8 hi, lo, re;
        #pragma unroll
        for (int j = 0; j < 8; ++j) {
            int Q = (int)lrintf(xv[j] * 16384.f);           // x * 2^14
            int d0 = ((Q + 256) & 511) - 256;               // [-256,255], exact bf16
            int d1 = (Q - d0) / 512;                        // |d1|<=~182, exact bf16
            float rr = xv[j] - (float)Q * (1.f / 16384.f);  // exact (Sterbenz)
            hi[j] = (bf16_t)(float)(d1 * 512);              // exact (pow2 shift)
            lo[j] = (bf16_t)(float)d0;
            re[j] = (bf16_t)(rr * 16384.f);                 // in [-.5,.5]
        }
        *(bf16x8*)&XLi[(size_t)r * 6144 + cb]        = hi;
        *(bf16x8*)&XLi[(size_t)r * 6144 + 3072 + cb] = lo;
        *(bf16x8*)&XLr[(size_t)r * 3072 + cb]        = re;
    }
}

__global__ __launch_bounds__(256) void prep_all(
    const float* __restrict__ W1, const float* __restrict__ W2,
    const float* __restrict__ W3, const float* __restrict__ W4,
    const float* __restrict__ x,
    bf16_t* __restrict__ sW1, int8_t* __restrict__ sW2,
    int8_t* __restrict__ sW3, int8_t* __restrict__ sW4,
    bf16_t* __restrict__ XLi, bf16_t* __restrict__ XLr,
    double* __restrict__ scD)
{
    const int g = blockIdx.x;
    if      (g < 2048)  prep_w1_row(W1, g, sW1, scD + 0);
    else if (g < 4096)  prep_wi8_row(W2, g - 2048, sW2, scD + 1);
    else if (g < 6144)  prep_wi8_row(W3, g - 4096, sW3, scD + 2);
    else if (g < 8192)  prep_wi8_row(W4, g - 6144, sW4, scD + 3);
    else                prep_x_row(x, g - 8192, XLi, XLr);
}

// ===== R11 merged L1 GEMM: z1 = mean|W1|*2^-14*(hi@s + lo@s + re@s) + b1 ====
// 128x128 output tile, BK=32, four 8-KiB LDS tiles {hi, lo, re, B}.
// One staged B-tile feeds 48 MFMA (3 A-streams x 16). accI exact integers;
// accR's MFMA order matches the old L1b exactly (k=0,32,64.. same fragments).
// Epilogue: s = (double)accI + (double)accR (exact, 42-bit span) -> identical
// doubles as the old Ti+Sr path => bit-identical p0 / habs.
__global__ __launch_bounds__(256) void gemm_l1(
    const bf16_t* __restrict__ XLi, const bf16_t* __restrict__ XLr,
    const bf16_t* __restrict__ Bs,              // sW1 single-copy [2048][3072]
    const double* __restrict__ sumW,
    const float* __restrict__ bias,
    int8_t* __restrict__ binOut,
    double* __restrict__ habs)
{
    __shared__ __align__(16) bf16_t sHi[128 * 32];
    __shared__ __align__(16) bf16_t sLo[128 * 32];
    __shared__ __align__(16) bf16_t sRe[128 * 32];
    __shared__ __align__(16) bf16_t sB [128 * 32];
    const int t = threadIdx.x;
    const int lane = t & 63;
    const int wave = t >> 6;
    const int wr = wave >> 1, wc = wave & 1;
    const int qa = lane >> 4, rA = lane & 15;
    const size_t bm = (size_t)blockIdx.y * 128, bn = (size_t)blockIdx.x * 128;

    f32x4 accI[4][4] = {};    // hi@s + lo@s : exact integers in fp32
    f32x4 accR[4][4] = {};    // re@s : same sequence as old L1b

    const bf16_t* HiB = XLi + bm * 6144;            // hi digits, row stride 6144
    const bf16_t* LoB = XLi + bm * 6144 + 3072;     // lo digits
    const bf16_t* ReB = XLr + bm * 3072;            // residual
    const bf16_t* BB  = Bs  + bn * 3072;            // signs (single copy)

    // 4-chunk rows (64 B): slot(row,cc) holds global chunk cc^(row&3);
    // reader wants global chunk qa -> slot qa^(row&3). row&3 == rA&3 for all
    // fragment rows (wr*64, wc*64, i*16 are all 0 mod 4).
    const int offk = (qa ^ (rA & 3)) * 8;
    const int arow = wr * 64 + rA;
    const int brow = wc * 64 + rA;

    for (int k0 = 0; k0 < 3072; k0 += 32) {
        #pragma unroll
        for (int i = 0; i < 2; ++i) {
            int c = i * 256 + t;
            int row = c >> 2, cc = c & 3;
            int ccg = cc ^ (row & 3);
            GLD_LDS16(HiB + (size_t)row * 6144 + k0 + ccg * 8, &sHi[c * 8]);
            GLD_LDS16(LoB + (size_t)row * 6144 + k0 + ccg * 8, &sLo[c * 8]);
            GLD_LDS16(ReB + (size_t)row * 3072 + k0 + ccg * 8, &sRe[c * 8]);
            GLD_LDS16(BB  + (size_t)row * 3072 + k0 + ccg * 8, &sB [c * 8]);
        }
        __syncthreads();

        bf16x8 fb[4];
        #pragma unroll
        for (int j = 0; j < 4; ++j)
            fb[j] = *(const bf16x8*)&sB[(brow + j * 16) * 32 + offk];
        {   // hi stream -> accI
            bf16x8 fa[4];
            #pragma unroll
            for (int i = 0; i < 4; ++i)
                fa[i] = *(const bf16x8*)&sHi[(arow + i * 16) * 32 + offk];
            #pragma unroll
            for (int i = 0; i < 4; ++i)
                #pragma unroll
                for (int j = 0; j < 4; ++j)
                    accI[i][j] = __builtin_amdgcn_mfma_f32_16x16x32_bf16(fa[i], fb[j], accI[i][j], 0, 0, 0);
        }
        {   // lo stream -> accI (integer adds commute exactly)
            bf16x8 fa[4];
            #pragma unroll
            for (int i = 0; i < 4; ++i)
                fa[i] = *(const bf16x8*)&sLo[(arow + i * 16) * 32 + offk];
            #pragma unroll
            for (int i = 0; i < 4; ++i)
                #pragma unroll
                for (int j = 0; j < 4; ++j)
                    accI[i][j] = __builtin_amdgcn_mfma_f32_16x16x32_bf16(fa[i], fb[j], accI[i][j], 0, 0, 0);
        }
        {   // re stream -> accR (k-order identical to old L1b)
            bf16x8 fa[4];
            #pragma unroll
            for (int i = 0; i < 4; ++i)
                fa[i] = *(const bf16x8*)&sRe[(arow + i * 16) * 32 + offk];
            #pragma unroll
            for (int i = 0; i < 4; ++i)
                #pragma unroll
                for (int j = 0; j < 4; ++j)
                    accR[i][j] = __builtin_amdgcn_mfma_f32_16x16x32_bf16(fa[i], fb[j], accR[i][j], 0, 0, 0);
        }
        __syncthreads();
    }

    const double scale = sumW[0] * (1.0 / 6144000.0) * (1.0 / 16384.0);
    double hs = 0.0;
    #pragma unroll
    for (int i = 0; i < 4; ++i) {
        #pragma unroll
        for (int j = 0; j < 4; ++j) {
            #pragma unroll
            for (int rr = 0; rr < 4; ++rr) {
                // C/D layout: col = lane&15, row = (lane>>4)*4 + reg
                int m = (int)bm + wr * 64 + i * 16 + qa * 4 + rr;
                int n = (int)bn + wc * 64 + j * 16 + rA;
                size_t idx = (size_t)m * 2048 + n;
                double s = (double)accR[i][j][rr] + (double)accI[i][j][rr];
                double z = s * scale + (n < 2000 ? (double)bias[n] : -1.0);
                binOut[idx] = (int8_t)(z > 0.0 ? 1 : 0);
                if (n < 2000 && z > 0.0) hs += z;
            }
        }
    }
    if (habs) block_reduce_atomic_d(hs, habs);
}

// i8 GEMM C = A @ B^T, A:[8192][2048] {0,1}, B:[2048][2048] {+-1,0}.
// 128x128 tile, BK=128, XOR-swizzled 16B chunks. Fragment loads split per
// k-half (32 live frag VGPRs instead of 64; integer sums order-independent).
__global__ __launch_bounds__(256, 4) void gemm_i8(
    const int8_t* __restrict__ A, const int8_t* __restrict__ B,
    const double* __restrict__ sumW, double invDivW,
    const double* __restrict__ sumH, double invDivH,
    const float* __restrict__ bias,
    int8_t* __restrict__ binOut, bf16_t* __restrict__ hOut,
    double* __restrict__ habs)
{
    const int K = 2048;                           // bytes per row
    __shared__ __align__(16) int8_t sA[128 * 128];
    __shared__ __align__(16) int8_t sB[128 * 128];
    const int t = threadIdx.x;
    const int lane = t & 63;
    const int wave = t >> 6;
    const int wr = wave >> 1, wc = wave & 1;
    const int qa = lane >> 4, rA = lane & 15;
    const size_t bm = (size_t)blockIdx.y * 128, bn = (size_t)blockIdx.x * 128;

    i32x4 acc[4][4] = {};

    const int8_t* Abase = A + bm * (size_t)K;
    const int8_t* Bbase = B + bn * (size_t)K;

    const int swz = rA & 7;
    const int offb0 = ((0 + qa) ^ swz) * 16;      // k-half 0: k in [0,64)
    const int offb1 = ((4 + qa) ^ swz) * 16;      // k-half 1: k in [64,128)
    const int arow = wr * 64 + rA;
    const int brow = wc * 64 + rA;

    for (int k0 = 0; k0 < K; k0 += 128) {
        #pragma unroll
        for (int i = 0; i < 4; ++i) {
            int c = i * 256 + t;
            int row = c >> 3, cc = c & 7;
            int ccg = cc ^ (row & 7);
            GLD_LDS16(Abase + (size_t)row * K + k0 + ccg * 16, &sA[c * 16]);
        }
        #pragma unroll
        for (int i = 0; i < 4; ++i) {
            int c = i * 256 + t;
            int row = c >> 3, cc = c & 7;
            int ccg = cc ^ (row & 7);
            GLD_LDS16(Bbase + (size_t)row * K + k0 + ccg * 16, &sB[c * 16]);
        }
        __syncthreads();

        {   // k-half 0
            i32x4 fa[4], fb[4];
            #pragma unroll
            for (int i = 0; i < 4; ++i) {
                fa[i] = *(const i32x4*)&sA[(arow + i * 16) * 128 + offb0];
                fb[i] = *(const i32x4*)&sB[(brow + i * 16) * 128 + offb0];
            }
            #pragma unroll
            for (int i = 0; i < 4; ++i)
                #pragma unroll
                for (int j = 0; j < 4; ++j)
                    acc[i][j] = __builtin_amdgcn_mfma_i32_16x16x64_i8(fa[i], fb[j], acc[i][j], 0, 0, 0);
        }
        {   // k-half 1
            i32x4 fa[4], fb[4];
            #pragma unroll
            for (int i = 0; i < 4; ++i) {
                fa[i] = *(const i32x4*)&sA[(arow + i * 16) * 128 + offb1];
                fb[i] = *(const i32x4*)&sB[(brow + i * 16) * 128 + offb1];
            }
            #pragma unroll
            for (int i = 0; i < 4; ++i)
                #pragma unroll
                for (int j = 0; j < 4; ++j)
                    acc[i][j] = __builtin_amdgcn_mfma_i32_16x16x64_i8(fa[i], fb[j], acc[i][j], 0, 0, 0);
        }
        __syncthreads();
    }

    const double scale = sumW[0] * invDivW * sumH[0] * invDivH;
    double hs = 0.0;
    #pragma unroll
    for (int i = 0; i < 4; ++i) {
        #pragma unroll
        for (int j = 0; j < 4; ++j) {
            #pragma unroll
            for (int rr = 0; rr < 4; ++rr) {
                int m = (int)bm + wr * 64 + i * 16 + qa * 4 + rr;
                int n = (int)bn + wc * 64 + j * 16 + rA;
                size_t idx = (size_t)m * 2048 + n;
                double z = (double)acc[i][j][rr] * scale +
                           (n < 2000 ? (double)bias[n] : -1.0);
                if (binOut) binOut[idx] = (int8_t)(z > 0.0 ? 1 : 0);
                if (hOut)   hOut[idx] = (bf16_t)(float)(z > 0.0 ? z : 0.0);
                if (n < 2000 && z > 0.0) hs += z;
            }
        }
    }
    if (habs) block_reduce_atomic_d(hs, habs);
}

// out[8192][10] = h4[:, :2000] @ W5.T + b5  (h4 bf16, memory-bound)
__global__ __launch_bounds__(256) void fc_final(
    const bf16_t* __restrict__ h4, const float* __restrict__ W5,
    const float* __restrict__ b5, float* __restrict__ out)
{
    const int r = blockIdx.x, t = threadIdx.x;
    float acc[10] = {};
    for (int k = t; k < 2000; k += 256) {
        float a = (float)h4[(size_t)r * 2048 + k];
        #pragma unroll
        for (int c = 0; c < 10; ++c) acc[c] += a * W5[c * 2000 + k];
    }
    __shared__ float red[4][10];
    #pragma unroll
    for (int c = 0; c < 10; ++c) {
        float v = acc[c];
        #pragma unroll
        for (int off = 32; off > 0; off >>= 1) v += __shfl_down(v, off);
        if ((t & 63) == 0) red[t >> 6][c] = v;
    }
    __syncthreads();
    if (t < 10) out[(size_t)r * 10 + t] = red[0][t] + red[1][t] + red[2][t] + red[3][t] + b5[t];
}

extern "C" void kernel_launch(void* const* d_in, const int* in_sizes, int n_in,
                              void* d_out, int out_size, void* d_ws, size_t ws_size,
                              hipStream_t stream)
{
    const float* x  = (const float*)d_in[0];
    const float* W1 = (const float*)d_in[1];
    const float* b1 = (const float*)d_in[2];
    const float* W2 = (const float*)d_in[3];
    const float* b2 = (const float*)d_in[4];
    const float* W3 = (const float*)d_in[5];
    const float* b3 = (const float*)d_in[6];
    const float* W4 = (const float*)d_in[7];
    const float* b4 = (const float*)d_in[8];
    const float* W5 = (const float*)d_in[9];
    const float* b5 = (const float*)d_in[10];
    float* out = (float*)d_out;
    (void)ws_size; (void)in_sizes; (void)n_in; (void)out_size;

    const size_t PH = (size_t)8192 * 2048;

    // Workspace layout unchanged from R6 (offsets preserved; sW1 now only
    // uses the first 12 MiB of its 24 MiB slot; Ti slot only used as h4).
    char* w = (char*)d_ws;
    double* scD = (double*)w;                     // [0..3]=sum|W1..4|, [4..6]=sum h1..3
    size_t off = 256;
    bf16_t* XLi = (bf16_t*)(w + off); off += (size_t)8192 * 6144 * 2;  // 96 MiB
    bf16_t* XLr = (bf16_t*)(w + off); off += (size_t)8192 * 3072 * 2;  // 48 MiB
    bf16_t* sW1 = (bf16_t*)(w + off); off += (size_t)2048 * 6144 * 2;  // 24 MiB slot (12 used)
    float*  Ti  = (float*)(w + off);  off += PH * 4;                   // 64 MiB (h4 alias only)
    int8_t* p0  = (int8_t*)(w + off); off += PH;                       // 16 MiB
    int8_t* sW2 = (int8_t*)(w + off); off += (size_t)2048 * 2048;      // 4 MiB
    int8_t* sW3 = (int8_t*)(w + off); off += (size_t)2048 * 2048;      // 4 MiB
    int8_t* sW4 = (int8_t*)(w + off); off += (size_t)2048 * 2048;      // 4 MiB
    int8_t* p1  = (int8_t*)XLi;                    // XLi dead after gemm_l1
    bf16_t* h4  = (bf16_t*)Ti;                     // Ti slot reused for h4

    hipMemsetAsync(w, 0, 256, stream);
    // one fused prep dispatch: W1 signs (bf16, single copy), W2-4 signs (i8), x limbs
    prep_all<<<16384, 256, 0, stream>>>(W1, W2, W3, W4, x,
                                        sW1, sW2, sW3, sW4, XLi, XLr, scD);

    dim3 grid(16, 64), blk(256);
    // Merged L1: p0 = bin(mean|W1| * 2^-14 * (hi@s + lo@s + re@s) + b1)
    gemm_l1<<<grid, blk, 0, stream>>>(XLi, XLr, sW1, scD + 0, b1, p0, scD + 4);

    // Layers 2-4: exact i8 GEMMs, double epilogue
    gemm_i8<<<grid, blk, 0, stream>>>(p0, sW2,
                                      scD + 1, 1.0 / 4000000.0, scD + 4, 1.0 / 16384000.0,
                                      b2, p1, nullptr, scD + 5);
    gemm_i8<<<grid, blk, 0, stream>>>(p1, sW3,
                                      scD + 2, 1.0 / 4000000.0, scD + 5, 1.0 / 16384000.0,
                                      b3, p0, nullptr, scD + 6);
    gemm_i8<<<grid, blk, 0, stream>>>(p0, sW4,
                                      scD + 3, 1.0 / 4000000.0, scD + 6, 1.0 / 16384000.0,
                                      b4, nullptr, h4, nullptr);
    fc_final<<<8192, 256, 0, stream>>>(h4, W5, b5, out);
}

// Round 7
// 838.585 us; speedup vs baseline: 1.3520x; 1.3520x over previous
//
#include <hip/hip_runtime.h>
#include <hip/hip_bf16.h>
#include <stdint.h>

// Binarized MLP: B=8192, D_IN=3072, H=2000 (pad 2048), C=10.
// L1 (exact, bf16 MFMA): Q=round(x*2^14)=d1*512+d0 digits exact in bf16;
//   L1a: Ti = hi@s + lo@s via SHARED-B K=3072 GEMM (R12) — replaces the
//   K=6144 [hi|lo]@[s|s] form: same exact integer sums (order-free, <2^24),
//   but B staged ONCE and 64 MFMA per barrier-pair instead of 32.
//   L1b: residual K=3072 GEMM + combine z1 = mean|W1|*2^-14*(Ti+Sr)+b1 (double)
//   — the PROVEN R6 gemm_bin, unchanged (B values identical, ldB=3072).
// Layers 2-4: i8 MFMA on {0,1}x{+-1} — exact i32, BK=128. h4 in bf16.
// R12 post-mortem of R11: merged 3-stream kernel died of 288 regs/wave
// (1 block/CU) + 64B-row bank conflicts (2.5e7). Fix: ONE accumulator,
// proven [128][64] tiles. LDS 48KiB -> 3 blocks/CU via __launch_bounds__(256,3)
// (NOT 4: that would cap regs at 128 and respill — R7 lesson).
typedef __bf16 bf16_t;
typedef __attribute__((ext_vector_type(8))) __bf16 bf16x8;
typedef __attribute__((ext_vector_type(4))) float f32x4;
typedef __attribute__((ext_vector_type(4))) int i32x4;
typedef __attribute__((ext_vector_type(8))) char i8x8;

#define GLD_LDS16(g, l) __builtin_amdgcn_global_load_lds( \
    (__attribute__((address_space(1))) void*)(g), \
    (__attribute__((address_space(3))) void*)(l), 16, 0, 0)

__device__ __forceinline__ void block_reduce_atomic_d(double v, double* dst) {
    #pragma unroll
    for (int off = 32; off > 0; off >>= 1) v += __shfl_down(v, off);
    __shared__ double rb[4];
    const int t = threadIdx.x;
    if ((t & 63) == 0) rb[t >> 6] = v;
    __syncthreads();
    if (t == 0) atomicAdd(dst, rb[0] + rb[1] + rb[2] + rb[3]);
}

// --- fused prep: one dispatch, 16384 blocks ---
// sW1 is SINGLE-copy [2048][3072] (R12: both L1 GEMMs read it directly).
__device__ __forceinline__ void prep_w1_row(
    const float* __restrict__ W, int r, bf16_t* __restrict__ S, double* sumOut)
{
    const int t = threadIdx.x;
    double sl = 0.0;
    for (int cb = t * 8; cb < 3072; cb += 2048) {
        bf16x8 o;
        if (r < 2000) {
            #pragma unroll
            for (int j = 0; j < 8; ++j) {
                float v = W[(size_t)r * 3072 + cb + j];
                sl += (double)fabsf(v);
                o[j] = (bf16_t)(v > 0.f ? 1.f : (v < 0.f ? -1.f : 0.f));
            }
        } else {
            #pragma unroll
            for (int j = 0; j < 8; ++j) o[j] = (bf16_t)0.f;
        }
        *(bf16x8*)&S[(size_t)r * 3072 + cb] = o;
    }
    block_reduce_atomic_d(sl, sumOut);
}

__device__ __forceinline__ void prep_wi8_row(
    const float* __restrict__ W, int r, int8_t* __restrict__ S, double* sumOut)
{
    const int t = threadIdx.x;
    const int cb = t * 8;
    double sl = 0.0;
    i8x8 o;
    if (r < 2000) {
        #pragma unroll
        for (int j = 0; j < 8; ++j) {
            int c = cb + j;
            float v = (c < 2000) ? W[(size_t)r * 2000 + c] : 0.f;
            sl += (double)fabsf(v);
            o[j] = (char)(v > 0.f ? 1 : (v < 0.f ? -1 : 0));
        }
    } else {
        #pragma unroll
        for (int j = 0; j < 8; ++j) o[j] = 0;
    }
    *(i8x8*)&S[(size_t)r * 2048 + cb] = o;
    block_reduce_atomic_d(sl, sumOut);
}

__device__ __forceinline__ void prep_x_row(
    const float* __restrict__ x, int r, bf16_t* __restrict__ XLi, bf16_t* __restrict__ XLr)
{
    const int t = threadIdx.x;
    for (int cb = t * 8; cb < 3072; cb += 2048) {
        float4 v0 = *(const float4*)&x[(size_t)r * 3072 + cb];
        float4 v1 = *(const float4*)&x[(size_t)r * 3072 + cb + 4];
        float xv[8] = {v0.x, v0.y, v0.z, v0.w, v1.x, v1.y, v1.z, v1.w};
        bf16x8 hi, lo, re;
        #pragma unroll
        for (int j = 0; j < 8; ++j) {
            int Q = (int)lrintf(xv[j] * 16384.f);           // x * 2^14
            int d0 = ((Q + 256) & 511) - 256;               // [-256,255], exact bf16
            int d1 = (Q - d0) / 512;                        // |d1|<=~182, exact bf16
            float rr = xv[j] - (float)Q * (1.f / 16384.f);  // exact (Sterbenz)
            hi[j] = (bf16_t)(float)(d1 * 512);              // exact (pow2 shift)
            lo[j] = (bf16_t)(float)d0;
            re[j] = (bf16_t)(rr * 16384.f);                 // in [-.5,.5]
        }
        *(bf16x8*)&XLi[(size_t)r * 6144 + cb]        = hi;
        *(bf16x8*)&XLi[(size_t)r * 6144 + 3072 + cb] = lo;
        *(bf16x8*)&XLr[(size_t)r * 3072 + cb]        = re;
    }
}

__global__ __launch_bounds__(256) void prep_all(
    const float* __restrict__ W1, const float* __restrict__ W2,
    const float* __restrict__ W3, const float* __restrict__ W4,
    const float* __restrict__ x,
    bf16_t* __restrict__ sW1, int8_t* __restrict__ sW2,
    int8_t* __restrict__ sW3, int8_t* __restrict__ sW4,
    bf16_t* __restrict__ XLi, bf16_t* __restrict__ XLr,
    double* __restrict__ scD)
{
    const int g = blockIdx.x;
    if      (g < 2048)  prep_w1_row(W1, g, sW1, scD + 0);
    else if (g < 4096)  prep_wi8_row(W2, g - 2048, sW2, scD + 1);
    else if (g < 6144)  prep_wi8_row(W3, g - 4096, sW3, scD + 2);
    else if (g < 8192)  prep_wi8_row(W4, g - 6144, sW4, scD + 3);
    else                prep_x_row(x, g - 8192, XLi, XLr);
}

// ===== R12 L1a: Ti = hi@s + lo@s, shared B-tile, K=3072, BK=64 ============
// Three [128][64] LDS tiles (proven swizzle, 0 conflicts). Per barrier-pair:
// 64 MFMA (hi+lo share each fb). ONE acc[4][4] (exact ints, order-free).
// 48KiB LDS -> 3 blocks/CU; (256,3) keeps the register budget comfortable.
__global__ __launch_bounds__(256, 3) void gemm_l1a(
    const bf16_t* __restrict__ XLi,             // [8192][6144] = [hi|lo]
    const bf16_t* __restrict__ Bs,              // [2048][3072] signs, single copy
    float* __restrict__ Ti)                     // [8192][2048] raw integer sums
{
    __shared__ __align__(16) bf16_t sHi[128 * 64];
    __shared__ __align__(16) bf16_t sLo[128 * 64];
    __shared__ __align__(16) bf16_t sB [128 * 64];
    const int t = threadIdx.x;
    const int lane = t & 63;
    const int wave = t >> 6;
    const int wr = wave >> 1, wc = wave & 1;
    const int qa = lane >> 4, rA = lane & 15;
    const size_t bm = (size_t)blockIdx.y * 128, bn = (size_t)blockIdx.x * 128;

    f32x4 acc[4][4] = {};

    const bf16_t* HiB = XLi + bm * 6144;            // hi digits (row stride 6144)
    const bf16_t* LoB = XLi + bm * 6144 + 3072;     // lo digits
    const bf16_t* BB  = Bs  + bn * 3072;            // signs

    const int swz = rA & 7;
    const int offk0 = ((0 + qa) ^ swz) * 8;
    const int offk1 = ((4 + qa) ^ swz) * 8;
    const int arow = wr * 64 + rA;
    const int brow = wc * 64 + rA;

    for (int k0 = 0; k0 < 3072; k0 += 64) {
        #pragma unroll
        for (int i = 0; i < 4; ++i) {
            int c = i * 256 + t;
            int row = c >> 3, cc = c & 7;
            int ccg = cc ^ (row & 7);
            GLD_LDS16(HiB + (size_t)row * 6144 + k0 + ccg * 8, &sHi[c * 8]);
            GLD_LDS16(LoB + (size_t)row * 6144 + k0 + ccg * 8, &sLo[c * 8]);
            GLD_LDS16(BB  + (size_t)row * 3072 + k0 + ccg * 8, &sB [c * 8]);
        }
        __syncthreads();

        #pragma unroll
        for (int h = 0; h < 2; ++h) {               // two k-halves per tile
            const int offk = h ? offk1 : offk0;
            bf16x8 fb[4];
            #pragma unroll
            for (int j = 0; j < 4; ++j)
                fb[j] = *(const bf16x8*)&sB[(brow + j * 16) * 64 + offk];
            bf16x8 fa[4];
            #pragma unroll
            for (int i = 0; i < 4; ++i)             // hi stream
                fa[i] = *(const bf16x8*)&sHi[(arow + i * 16) * 64 + offk];
            #pragma unroll
            for (int i = 0; i < 4; ++i)
                #pragma unroll
                for (int j = 0; j < 4; ++j)
                    acc[i][j] = __builtin_amdgcn_mfma_f32_16x16x32_bf16(fa[i], fb[j], acc[i][j], 0, 0, 0);
            #pragma unroll
            for (int i = 0; i < 4; ++i)             // lo stream (reuses fb)
                fa[i] = *(const bf16x8*)&sLo[(arow + i * 16) * 64 + offk];
            #pragma unroll
            for (int i = 0; i < 4; ++i)
                #pragma unroll
                for (int j = 0; j < 4; ++j)
                    acc[i][j] = __builtin_amdgcn_mfma_f32_16x16x32_bf16(fa[i], fb[j], acc[i][j], 0, 0, 0);
        }
        __syncthreads();
    }

    // raw write: exact integer partial sums in fp32 (same values as R6's L1a)
    #pragma unroll
    for (int i = 0; i < 4; ++i)
        #pragma unroll
        for (int j = 0; j < 4; ++j)
            #pragma unroll
            for (int rr = 0; rr < 4; ++rr) {
                int m = (int)bm + wr * 64 + i * 16 + qa * 4 + rr;
                int n = (int)bn + wc * 64 + j * 16 + rA;
                Ti[(size_t)m * 2048 + n] = acc[i][j][rr];
            }
}

// bf16 GEMM C = A @ B^T, 128x128x64 tiles (PROVEN R6 form). rawOut mode
// writes fp32 acc. Epilogue (double): z = sumW*invDivW*extraScale*
// (acc+addPlane?) + bias; binOut i8 {0,1}; atomic double sum(relu z).
__global__ __launch_bounds__(256, 4) void gemm_bin(
    const bf16_t* __restrict__ A, const bf16_t* __restrict__ B, int K, int ldB,
    float* __restrict__ rawOut,
    const float* __restrict__ addPlane,
    const double* __restrict__ sumW, double invDivW, double extraScale,
    const float* __restrict__ bias,
    int8_t* __restrict__ binOut,
    double* __restrict__ habs)
{
    __shared__ __align__(16) bf16_t sA[128 * 64];
    __shared__ __align__(16) bf16_t sB[128 * 64];
    const int t = threadIdx.x;
    const int lane = t & 63;
    const int wave = t >> 6;
    const int wr = wave >> 1, wc = wave & 1;
    const int qa = lane >> 4, rA = lane & 15;
    const size_t bm = (size_t)blockIdx.y * 128, bn = (size_t)blockIdx.x * 128;

    f32x4 acc[4][4] = {};

    const bf16_t* Abase = A + bm * (size_t)K;
    const bf16_t* Bbase = B + bn * (size_t)ldB;

    const int swz = rA & 7;
    const int offk0 = ((0 + qa) ^ swz) * 8;
    const int offk1 = ((4 + qa) ^ swz) * 8;
    const int arow = wr * 64 + rA;
    const int brow = wc * 64 + rA;

    for (int k0 = 0; k0 < K; k0 += 64) {
        #pragma unroll
        for (int i = 0; i < 4; ++i) {
            int c = i * 256 + t;
            int row = c >> 3, cc = c & 7;
            int ccg = cc ^ (row & 7);
            GLD_LDS16(Abase + (size_t)row * K + k0 + ccg * 8, &sA[c * 8]);
        }
        #pragma unroll
        for (int i = 0; i < 4; ++i) {
            int c = i * 256 + t;
            int row = c >> 3, cc = c & 7;
            int ccg = cc ^ (row & 7);
            GLD_LDS16(Bbase + (size_t)row * ldB + k0 + ccg * 8, &sB[c * 8]);
        }
        __syncthreads();

        bf16x8 fa[4][2], fb[4][2];
        #pragma unroll
        for (int i = 0; i < 4; ++i) {
            fa[i][0] = *(const bf16x8*)&sA[(arow + i * 16) * 64 + offk0];
            fa[i][1] = *(const bf16x8*)&sA[(arow + i * 16) * 64 + offk1];
            fb[i][0] = *(const bf16x8*)&sB[(brow + i * 16) * 64 + offk0];
            fb[i][1] = *(const bf16x8*)&sB[(brow + i * 16) * 64 + offk1];
        }
        #pragma unroll
        for (int i = 0; i < 4; ++i)
            #pragma unroll
            for (int j = 0; j < 4; ++j) {
                acc[i][j] = __builtin_amdgcn_mfma_f32_16x16x32_bf16(fa[i][0], fb[j][0], acc[i][j], 0, 0, 0);
                acc[i][j] = __builtin_amdgcn_mfma_f32_16x16x32_bf16(fa[i][1], fb[j][1], acc[i][j], 0, 0, 0);
            }
        __syncthreads();
    }

    if (rawOut) {   // exact integer partial sums in fp32
        #pragma unroll
        for (int i = 0; i < 4; ++i)
            #pragma unroll
            for (int j = 0; j < 4; ++j)
                #pragma unroll
                for (int rr = 0; rr < 4; ++rr) {
                    int m = (int)bm + wr * 64 + i * 16 + qa * 4 + rr;
                    int n = (int)bn + wc * 64 + j * 16 + rA;
                    rawOut[(size_t)m * 2048 + n] = acc[i][j][rr];
                }
        return;
    }

    const double scale = sumW[0] * invDivW * extraScale;
    double hs = 0.0;
    #pragma unroll
    for (int i = 0; i < 4; ++i) {
        #pragma unroll
        for (int j = 0; j < 4; ++j) {
            #pragma unroll
            for (int rr = 0; rr < 4; ++rr) {
                // C/D layout: col = lane&15, row = (lane>>4)*4 + reg
                int m = (int)bm + wr * 64 + i * 16 + qa * 4 + rr;
                int n = (int)bn + wc * 64 + j * 16 + rA;
                size_t idx = (size_t)m * 2048 + n;
                double s = (double)acc[i][j][rr];
                if (addPlane) s += (double)addPlane[idx];
                double z = s * scale + (n < 2000 ? (double)bias[n] : -1.0);
                binOut[idx] = (int8_t)(z > 0.0 ? 1 : 0);
                if (n < 2000 && z > 0.0) hs += z;
            }
        }
    }
    if (habs) block_reduce_atomic_d(hs, habs);
}

// i8 GEMM C = A @ B^T, A:[8192][2048] {0,1}, B:[2048][2048] {+-1,0}.
// 128x128 tile, BK=128, XOR-swizzled 16B chunks. Fragment loads split per
// k-half (32 live frag VGPRs instead of 64; integer sums order-independent).
__global__ __launch_bounds__(256, 4) void gemm_i8(
    const int8_t* __restrict__ A, const int8_t* __restrict__ B,
    const double* __restrict__ sumW, double invDivW,
    const double* __restrict__ sumH, double invDivH,
    const float* __restrict__ bias,
    int8_t* __restrict__ binOut, bf16_t* __restrict__ hOut,
    double* __restrict__ habs)
{
    const int K = 2048;                           // bytes per row
    __shared__ __align__(16) int8_t sA[128 * 128];
    __shared__ __align__(16) int8_t sB[128 * 128];
    const int t = threadIdx.x;
    const int lane = t & 63;
    const int wave = t >> 6;
    const int wr = wave >> 1, wc = wave & 1;
    const int qa = lane >> 4, rA = lane & 15;
    const size_t bm = (size_t)blockIdx.y * 128, bn = (size_t)blockIdx.x * 128;

    i32x4 acc[4][4] = {};

    const int8_t* Abase = A + bm * (size_t)K;
    const int8_t* Bbase = B + bn * (size_t)K;

    const int swz = rA & 7;
    const int offb0 = ((0 + qa) ^ swz) * 16;      // k-half 0: k in [0,64)
    const int offb1 = ((4 + qa) ^ swz) * 16;      // k-half 1: k in [64,128)
    const int arow = wr * 64 + rA;
    const int brow = wc * 64 + rA;

    for (int k0 = 0; k0 < K; k0 += 128) {
        #pragma unroll
        for (int i = 0; i < 4; ++i) {
            int c = i * 256 + t;
            int row = c >> 3, cc = c & 7;
            int ccg = cc ^ (row & 7);
            GLD_LDS16(Abase + (size_t)row * K + k0 + ccg * 16, &sA[c * 16]);
        }
        #pragma unroll
        for (int i = 0; i < 4; ++i) {
            int c = i * 256 + t;
            int row = c >> 3, cc = c & 7;
            int ccg = cc ^ (row & 7);
            GLD_LDS16(Bbase + (size_t)row * K + k0 + ccg * 16, &sB[c * 16]);
        }
        __syncthreads();

        {   // k-half 0
            i32x4 fa[4], fb[4];
            #pragma unroll
            for (int i = 0; i < 4; ++i) {
                fa[i] = *(const i32x4*)&sA[(arow + i * 16) * 128 + offb0];
                fb[i] = *(const i32x4*)&sB[(brow + i * 16) * 128 + offb0];
            }
            #pragma unroll
            for (int i = 0; i < 4; ++i)
                #pragma unroll
                for (int j = 0; j < 4; ++j)
                    acc[i][j] = __builtin_amdgcn_mfma_i32_16x16x64_i8(fa[i], fb[j], acc[i][j], 0, 0, 0);
        }
        {   // k-half 1
            i32x4 fa[4], fb[4];
            #pragma unroll
            for (int i = 0; i < 4; ++i) {
                fa[i] = *(const i32x4*)&sA[(arow + i * 16) * 128 + offb1];
                fb[i] = *(const i32x4*)&sB[(brow + i * 16) * 128 + offb1];
            }
            #pragma unroll
            for (int i = 0; i < 4; ++i)
                #pragma unroll
                for (int j = 0; j < 4; ++j)
                    acc[i][j] = __builtin_amdgcn_mfma_i32_16x16x64_i8(fa[i], fb[j], acc[i][j], 0, 0, 0);
        }
        __syncthreads();
    }

    const double scale = sumW[0] * invDivW * sumH[0] * invDivH;
    double hs = 0.0;
    #pragma unroll
    for (int i = 0; i < 4; ++i) {
        #pragma unroll
        for (int j = 0; j < 4; ++j) {
            #pragma unroll
            for (int rr = 0; rr < 4; ++rr) {
                int m = (int)bm + wr * 64 + i * 16 + qa * 4 + rr;
                int n = (int)bn + wc * 64 + j * 16 + rA;
                size_t idx = (size_t)m * 2048 + n;
                double z = (double)acc[i][j][rr] * scale +
                           (n < 2000 ? (double)bias[n] : -1.0);
                if (binOut) binOut[idx] = (int8_t)(z > 0.0 ? 1 : 0);
                if (hOut)   hOut[idx] = (bf16_t)(float)(z > 0.0 ? z : 0.0);
                if (n < 2000 && z > 0.0) hs += z;
            }
        }
    }
    if (habs) block_reduce_atomic_d(hs, habs);
}

// out[8192][10] = h4[:, :2000] @ W5.T + b5  (h4 bf16, memory-bound)
__global__ __launch_bounds__(256) void fc_final(
    const bf16_t* __restrict__ h4, const float* __restrict__ W5,
    const float* __restrict__ b5, float* __restrict__ out)
{
    const int r = blockIdx.x, t = threadIdx.x;
    float acc[10] = {};
    for (int k = t; k < 2000; k += 256) {
        float a = (float)h4[(size_t)r * 2048 + k];
        #pragma unroll
        for (int c = 0; c < 10; ++c) acc[c] += a * W5[c * 2000 + k];
    }
    __shared__ float red[4][10];
    #pragma unroll
    for (int c = 0; c < 10; ++c) {
        float v = acc[c];
        #pragma unroll
        for (int off = 32; off > 0; off >>= 1) v += __shfl_down(v, off);
        if ((t & 63) == 0) red[t >> 6][c] = v;
    }
    __syncthreads();
    if (t < 10) out[(size_t)r * 10 + t] = red[0][t] + red[1][t] + red[2][t] + red[3][t] + b5[t];
}

extern "C" void kernel_launch(void* const* d_in, const int* in_sizes, int n_in,
                              void* d_out, int out_size, void* d_ws, size_t ws_size,
                              hipStream_t stream)
{
    const float* x  = (const float*)d_in[0];
    const float* W1 = (const float*)d_in[1];
    const float* b1 = (const float*)d_in[2];
    const float* W2 = (const float*)d_in[3];
    const float* b2 = (const float*)d_in[4];
    const float* W3 = (const float*)d_in[5];
    const float* b3 = (const float*)d_in[6];
    const float* W4 = (const float*)d_in[7];
    const float* b4 = (const float*)d_in[8];
    const float* W5 = (const float*)d_in[9];
    const float* b5 = (const float*)d_in[10];
    float* out = (float*)d_out;
    (void)ws_size; (void)in_sizes; (void)n_in; (void)out_size;

    const size_t PH = (size_t)8192 * 2048;

    // Workspace layout unchanged from R6 (260.3 MiB; 264 proven safe).
    // sW1 slot now holds the single-copy [2048][3072] signs (12 of 24 MiB).
    char* w = (char*)d_ws;
    double* scD = (double*)w;                     // [0..3]=sum|W1..4|, [4..6]=sum h1..3
    size_t off = 256;
    bf16_t* XLi = (bf16_t*)(w + off); off += (size_t)8192 * 6144 * 2;  // 96 MiB
    bf16_t* XLr = (bf16_t*)(w + off); off += (size_t)8192 * 3072 * 2;  // 48 MiB
    bf16_t* sW1 = (bf16_t*)(w + off); off += (size_t)2048 * 6144 * 2;  // 24 MiB slot (12 used)
    float*  Ti  = (float*)(w + off);  off += PH * 4;                   // 64 MiB
    int8_t* p0  = (int8_t*)(w + off); off += PH;                       // 16 MiB
    int8_t* sW2 = (int8_t*)(w + off); off += (size_t)2048 * 2048;      // 4 MiB
    int8_t* sW3 = (int8_t*)(w + off); off += (size_t)2048 * 2048;      // 4 MiB
    int8_t* sW4 = (int8_t*)(w + off); off += (size_t)2048 * 2048;      // 4 MiB
    int8_t* p1  = (int8_t*)XLi;                    // XLi dead after gemm_l1a
    bf16_t* h4  = (bf16_t*)Ti;                     // Ti dead after L1b epilogue

    hipMemsetAsync(w, 0, 256, stream);
    // one fused prep dispatch: W1 signs (single copy), W2-4 signs (i8), x limbs
    prep_all<<<16384, 256, 0, stream>>>(W1, W2, W3, W4, x,
                                        sW1, sW2, sW3, sW4, XLi, XLr, scD);

    dim3 grid(16, 64), blk(256);
    // L1a (R12): Ti = hi@s + lo@s, shared B-tile, 64 MFMA/barrier-pair
    gemm_l1a<<<grid, blk, 0, stream>>>(XLi, sW1, Ti);
    // L1b: residual GEMM + fused combine (PROVEN form, ldB=3072 single-copy s)
    gemm_bin<<<grid, blk, 0, stream>>>(XLr, sW1, 3072, 3072, nullptr, Ti,
                                       scD + 0, 1.0 / 6144000.0, 1.0 / 16384.0,
                                       b1, p0, scD + 4);

    // Layers 2-4: exact i8 GEMMs, double epilogue
    gemm_i8<<<grid, blk, 0, stream>>>(p0, sW2,
                                      scD + 1, 1.0 / 4000000.0, scD + 4, 1.0 / 16384000.0,
                                      b2, p1, nullptr, scD + 5);
    gemm_i8<<<grid, blk, 0, stream>>>(p1, sW3,
                                      scD + 2, 1.0 / 4000000.0, scD + 5, 1.0 / 16384000.0,
                                      b3, p0, nullptr, scD + 6);
    gemm_i8<<<grid, blk, 0, stream>>>(p0, sW4,
                                      scD + 3, 1.0 / 4000000.0, scD + 6, 1.0 / 16384000.0,
                                      b4, nullptr, h4, nullptr);
    fc_final<<<8192, 256, 0, stream>>>(h4, W5, b5, out);
}

// Round 8
// 804.011 us; speedup vs baseline: 1.4101x; 1.0430x over previous
//
#include <hip/hip_runtime.h>
#include <hip/hip_bf16.h>
#include <stdint.h>

// Binarized MLP: B=8192, D_IN=3072, H=2000 (pad 2048), C=10.
// L1 (exact, bf16 MFMA): Q=round(x*2^14)=d1*512+d0 digits exact in bf16;
//   L1a (R13): Ti = [hi|lo]@[s|s]^T K=6144 via 256x256 8-phase counted-vmcnt
//   schedule (8 waves, BK=64, 128KiB dbuf LDS, vmcnt(6), setprio) — the
//   m201-class structure. Exact integer sums, order-free -> Ti identical.
//   L1b: residual K=3072 GEMM + combine z1 = mean|W1|*2^-14*(Ti+Sr)+b1
//   (double) — PROVEN R6 gemm_bin, ldB=6144 (sW1 re-duplicated [s|s]).
// Layers 2-4: i8 MFMA on {0,1}x{+-1} — exact i32, BK=128. h4 in bf16.
// R13 rationale: R12's l1a sits at the 2-barrier 128² ceiling (MfmaUtil 42%,
// VALU 15%, HBM 31%, conflicts 0 — 211us). Only a deeper schedule moves it.
// Schedule invariants (derived, match guide template):
//  - per K-tile t: 4 quadrant phases x {ds_read frags; 2 gld_lds stage;
//    barrier; setprio(1); 16 MFMA; setprio(0); [q3: vmcnt] barrier}
//  - stage plan: q0 -> A-tail of t+1 (other buf); q1/q2 -> B of t+2 (this
//    buf, region consumed at q0); q3 -> A-head of t+2 (rows consumed q0/q1).
//  - boundary vmcnt(6): leaves exactly t+2's 6 staged rounds in flight.
//  - end barrier of each phase globally retires that phase's ds_reads before
//    the next phase's gld_lds overwrite (in-order DS retirement + reg deps).
typedef __bf16 bf16_t;
typedef __attribute__((ext_vector_type(8))) __bf16 bf16x8;
typedef __attribute__((ext_vector_type(4))) float f32x4;
typedef __attribute__((ext_vector_type(4))) int i32x4;
typedef __attribute__((ext_vector_type(8))) char i8x8;

#define GLD_LDS16(g, l) __builtin_amdgcn_global_load_lds( \
    (__attribute__((address_space(1))) void*)(g), \
    (__attribute__((address_space(3))) void*)(l), 16, 0, 0)

__device__ __forceinline__ void block_reduce_atomic_d(double v, double* dst) {
    #pragma unroll
    for (int off = 32; off > 0; off >>= 1) v += __shfl_down(v, off);
    __shared__ double rb[4];
    const int t = threadIdx.x;
    if ((t & 63) == 0) rb[t >> 6] = v;
    __syncthreads();
    if (t == 0) atomicAdd(dst, rb[0] + rb[1] + rb[2] + rb[3]);
}

// --- fused prep: one dispatch, 16384 blocks ---
// sW1 is the R6 DUPLICATED [s|s] form again (ld 6144): L1a-8ph consumes the
// standard-GEMM K=6144 formulation; L1b reads it with ldB=6144 (proven).
__device__ __forceinline__ void prep_w1_row(
    const float* __restrict__ W, int r, bf16_t* __restrict__ S, double* sumOut)
{
    const int t = threadIdx.x;
    double sl = 0.0;
    for (int cb = t * 8; cb < 3072; cb += 2048) {
        bf16x8 o;
        if (r < 2000) {
            #pragma unroll
            for (int j = 0; j < 8; ++j) {
                float v = W[(size_t)r * 3072 + cb + j];
                sl += (double)fabsf(v);
                o[j] = (bf16_t)(v > 0.f ? 1.f : (v < 0.f ? -1.f : 0.f));
            }
        } else {
            #pragma unroll
            for (int j = 0; j < 8; ++j) o[j] = (bf16_t)0.f;
        }
        *(bf16x8*)&S[(size_t)r * 6144 + cb] = o;
        *(bf16x8*)&S[(size_t)r * 6144 + 3072 + cb] = o;
    }
    block_reduce_atomic_d(sl, sumOut);
}

__device__ __forceinline__ void prep_wi8_row(
    const float* __restrict__ W, int r, int8_t* __restrict__ S, double* sumOut)
{
    const int t = threadIdx.x;
    const int cb = t * 8;
    double sl = 0.0;
    i8x8 o;
    if (r < 2000) {
        #pragma unroll
        for (int j = 0; j < 8; ++j) {
            int c = cb + j;
            float v = (c < 2000) ? W[(size_t)r * 2000 + c] : 0.f;
            sl += (double)fabsf(v);
            o[j] = (char)(v > 0.f ? 1 : (v < 0.f ? -1 : 0));
        }
    } else {
        #pragma unroll
        for (int j = 0; j < 8; ++j) o[j] = 0;
    }
    *(i8x8*)&S[(size_t)r * 2048 + cb] = o;
    block_reduce_atomic_d(sl, sumOut);
}

__device__ __forceinline__ void prep_x_row(
    const float* __restrict__ x, int r, bf16_t* __restrict__ XLi, bf16_t* __restrict__ XLr)
{
    const int t = threadIdx.x;
    for (int cb = t * 8; cb < 3072; cb += 2048) {
        float4 v0 = *(const float4*)&x[(size_t)r * 3072 + cb];
        float4 v1 = *(const float4*)&x[(size_t)r * 3072 + cb + 4];
        float xv[8] = {v0.x, v0.y, v0.z, v0.w, v1.x, v1.y, v1.z, v1.w};
        bf16x8 hi, lo, re;
        #pragma unroll
        for (int j = 0; j < 8; ++j) {
            int Q = (int)lrintf(xv[j] * 16384.f);           // x * 2^14
            int d0 = ((Q + 256) & 511) - 256;               // [-256,255], exact bf16
            int d1 = (Q - d0) / 512;                        // |d1|<=~182, exact bf16
            float rr = xv[j] - (float)Q * (1.f / 16384.f);  // exact (Sterbenz)
            hi[j] = (bf16_t)(float)(d1 * 512);              // exact (pow2 shift)
            lo[j] = (bf16_t)(float)d0;
            re[j] = (bf16_t)(rr * 16384.f);                 // in [-.5,.5]
        }
        *(bf16x8*)&XLi[(size_t)r * 6144 + cb]        = hi;
        *(bf16x8*)&XLi[(size_t)r * 6144 + 3072 + cb] = lo;
        *(bf16x8*)&XLr[(size_t)r * 3072 + cb]        = re;
    }
}

__global__ __launch_bounds__(256) void prep_all(
    const float* __restrict__ W1, const float* __restrict__ W2,
    const float* __restrict__ W3, const float* __restrict__ W4,
    const float* __restrict__ x,
    bf16_t* __restrict__ sW1, int8_t* __restrict__ sW2,
    int8_t* __restrict__ sW3, int8_t* __restrict__ sW4,
    bf16_t* __restrict__ XLi, bf16_t* __restrict__ XLr,
    double* __restrict__ scD)
{
    const int g = blockIdx.x;
    if      (g < 2048)  prep_w1_row(W1, g, sW1, scD + 0);
    else if (g < 4096)  prep_wi8_row(W2, g - 2048, sW2, scD + 1);
    else if (g < 6144)  prep_wi8_row(W3, g - 4096, sW3, scD + 2);
    else if (g < 8192)  prep_wi8_row(W4, g - 6144, sW4, scD + 3);
    else                prep_x_row(x, g - 8192, XLi, XLr);
}

// ===== R13 L1a: 256x256 8-phase GEMM, K=6144, counted vmcnt ================
// Grid 256 blocks (=256 CUs exactly), 512 threads = 8 waves (2M x 4N).
// Per wave: 128x64 output = acc[8][4] f32x4 (128 AGPRs). BK=64.
// LDS: lds[buf][op A/B][half][128*64] = 128 KiB. Stage round = 8 KiB
// (512 thr x 16B, dest linear in tid -> gld_lds-legal; src chunk XOR-swz).
__global__ __launch_bounds__(512, 2) void gemm_l1a8(
    const bf16_t* __restrict__ A,               // XLi [8192][6144]
    const bf16_t* __restrict__ B,               // sW1 [2048][6144] ([s|s])
    float* __restrict__ Ti)                     // [8192][2048]
{
    __shared__ __align__(16) bf16_t lds[2][2][2][128 * 64];
    const int tid = threadIdx.x;
    const int lane = tid & 63, wid = tid >> 6;
    const int wr = wid >> 2, wc = wid & 3;
    const int rA = lane & 15, qa = lane >> 4;

    // XCD-aware bijective swizzle (nwg=256, 256%8==0)
    const int fid = (int)blockIdx.x;
    const int sid = (fid & 7) * 32 + (fid >> 3);
    const size_t bm = (size_t)(sid >> 3) * 256;
    const size_t bn = (size_t)(sid & 7) * 256;

    const bf16_t* Ab = A + bm * 6144;
    const bf16_t* Bb = B + bn * 6144;

    // staging thread map: round = 64 rows x 64 cols; dest elem = tid*8
    const int sr = tid >> 3;                          // 0..63 row in round
    const int sgoff = ((tid & 7) ^ (sr & 7)) * 8;     // swizzled src col (elems)
    const int sdoff = tid * 8;                        // linear dest (elems)

#define STG(b_, o_, h_, r_, kt_) \
    GLD_LDS16(((o_) ? Bb : Ab) + (size_t)((h_) * 128 + (r_) * 64 + sr) * 6144 \
              + (kt_) * 64 + sgoff, \
              &lds[b_][o_][h_][(r_) * 4096 + sdoff])

    // prologue: tile0 fully (8 rounds), then tile1 {B x4, A-head x2}
    STG(0, 0, 0, 0, 0); STG(0, 0, 0, 1, 0); STG(0, 0, 1, 0, 0); STG(0, 0, 1, 1, 0);
    STG(0, 1, 0, 0, 0); STG(0, 1, 0, 1, 0); STG(0, 1, 1, 0, 0); STG(0, 1, 1, 1, 0);
    STG(1, 1, 0, 0, 1); STG(1, 1, 0, 1, 1); STG(1, 1, 1, 0, 1); STG(1, 1, 1, 1, 1);
    STG(1, 0, 0, 0, 1); STG(1, 0, 1, 0, 1);
    asm volatile("s_waitcnt vmcnt(6)" ::: "memory");   // tile0 resident
    __builtin_amdgcn_s_barrier();

    const int offk0 = ((0 + qa) ^ (rA & 7)) * 8;
    const int offk1 = ((4 + qa) ^ (rA & 7)) * 8;
    const int browb = (wc & 1) * 64;
    const int bhalf = wc >> 1;

    f32x4 acc[8][4] = {};

    for (int t = 0; t < 96; ++t) {
        const int p = t & 1;
        const bf16_t* Al = lds[p][0][wr];
        const bf16_t* Bl = lds[p][1][bhalf];

        bf16x8 fb[4][2];
        #pragma unroll
        for (int q = 0; q < 4; ++q) {
            if (q == 0) {                               // all B frags, held in regs
                #pragma unroll
                for (int n = 0; n < 4; ++n) {
                    fb[n][0] = *(const bf16x8*)&Bl[(browb + n * 16 + rA) * 64 + offk0];
                    fb[n][1] = *(const bf16x8*)&Bl[(browb + n * 16 + rA) * 64 + offk1];
                }
            }
            bf16x8 fa[2][2];
            #pragma unroll
            for (int mm = 0; mm < 2; ++mm) {
                fa[mm][0] = *(const bf16x8*)&Al[((q * 2 + mm) * 16 + rA) * 64 + offk0];
                fa[mm][1] = *(const bf16x8*)&Al[((q * 2 + mm) * 16 + rA) * 64 + offk1];
            }
            // stage plan (2 gld_lds per phase; guards uniform across block)
            if (q == 0) {
                if (t < 95) { STG(p ^ 1, 0, 0, 1, t + 1); STG(p ^ 1, 0, 1, 1, t + 1); }
            } else if (t < 94) {
                if (q == 1)      { STG(p, 1, 0, 0, t + 2); STG(p, 1, 0, 1, t + 2); }
                else if (q == 2) { STG(p, 1, 1, 0, t + 2); STG(p, 1, 1, 1, t + 2); }
                else             { STG(p, 0, 0, 0, t + 2); STG(p, 0, 1, 0, t + 2); }
            }
            __builtin_amdgcn_s_barrier();
            __builtin_amdgcn_s_setprio(1);
            #pragma unroll
            for (int mm = 0; mm < 2; ++mm)
                #pragma unroll
                for (int n = 0; n < 4; ++n) {
                    acc[q * 2 + mm][n] = __builtin_amdgcn_mfma_f32_16x16x32_bf16(
                        fa[mm][0], fb[n][0], acc[q * 2 + mm][n], 0, 0, 0);
                    acc[q * 2 + mm][n] = __builtin_amdgcn_mfma_f32_16x16x32_bf16(
                        fa[mm][1], fb[n][1], acc[q * 2 + mm][n], 0, 0, 0);
                }
            __builtin_amdgcn_s_setprio(0);
            if (q == 3) {
                if (t < 94) asm volatile("s_waitcnt vmcnt(6)" ::: "memory");
                else        asm volatile("s_waitcnt vmcnt(0)" ::: "memory");
            }
            __builtin_amdgcn_s_barrier();
        }
    }
#undef STG

    // epilogue: raw exact-integer sums (identical values to R6 L1a)
    #pragma unroll
    for (int m = 0; m < 8; ++m)
        #pragma unroll
        for (int n = 0; n < 4; ++n)
            #pragma unroll
            for (int rr = 0; rr < 4; ++rr) {
                size_t mm = bm + wr * 128 + m * 16 + qa * 4 + rr;
                size_t nn = bn + wc * 64 + n * 16 + rA;
                Ti[mm * 2048 + nn] = acc[m][n][rr];
            }
}

// bf16 GEMM C = A @ B^T, 128x128x64 tiles (PROVEN R6 form).
// Epilogue (double): z = sumW*invDivW*extraScale*(acc+addPlane?) + bias;
// binOut i8 {0,1}; atomic double sum(relu z).
__global__ __launch_bounds__(256, 4) void gemm_bin(
    const bf16_t* __restrict__ A, const bf16_t* __restrict__ B, int K, int ldB,
    float* __restrict__ rawOut,
    const float* __restrict__ addPlane,
    const double* __restrict__ sumW, double invDivW, double extraScale,
    const float* __restrict__ bias,
    int8_t* __restrict__ binOut,
    double* __restrict__ habs)
{
    __shared__ __align__(16) bf16_t sA[128 * 64];
    __shared__ __align__(16) bf16_t sB[128 * 64];
    const int t = threadIdx.x;
    const int lane = t & 63;
    const int wave = t >> 6;
    const int wr = wave >> 1, wc = wave & 1;
    const int qa = lane >> 4, rA = lane & 15;
    const size_t bm = (size_t)blockIdx.y * 128, bn = (size_t)blockIdx.x * 128;

    f32x4 acc[4][4] = {};

    const bf16_t* Abase = A + bm * (size_t)K;
    const bf16_t* Bbase = B + bn * (size_t)ldB;

    const int swz = rA & 7;
    const int offk0 = ((0 + qa) ^ swz) * 8;
    const int offk1 = ((4 + qa) ^ swz) * 8;
    const int arow = wr * 64 + rA;
    const int brow = wc * 64 + rA;

    for (int k0 = 0; k0 < K; k0 += 64) {
        #pragma unroll
        for (int i = 0; i < 4; ++i) {
            int c = i * 256 + t;
            int row = c >> 3, cc = c & 7;
            int ccg = cc ^ (row & 7);
            GLD_LDS16(Abase + (size_t)row * K + k0 + ccg * 8, &sA[c * 8]);
        }
        #pragma unroll
        for (int i = 0; i < 4; ++i) {
            int c = i * 256 + t;
            int row = c >> 3, cc = c & 7;
            int ccg = cc ^ (row & 7);
            GLD_LDS16(Bbase + (size_t)row * ldB + k0 + ccg * 8, &sB[c * 8]);
        }
        __syncthreads();

        bf16x8 fa[4][2], fb[4][2];
        #pragma unroll
        for (int i = 0; i < 4; ++i) {
            fa[i][0] = *(const bf16x8*)&sA[(arow + i * 16) * 64 + offk0];
            fa[i][1] = *(const bf16x8*)&sA[(arow + i * 16) * 64 + offk1];
            fb[i][0] = *(const bf16x8*)&sB[(brow + i * 16) * 64 + offk0];
            fb[i][1] = *(const bf16x8*)&sB[(brow + i * 16) * 64 + offk1];
        }
        #pragma unroll
        for (int i = 0; i < 4; ++i)
            #pragma unroll
            for (int j = 0; j < 4; ++j) {
                acc[i][j] = __builtin_amdgcn_mfma_f32_16x16x32_bf16(fa[i][0], fb[j][0], acc[i][j], 0, 0, 0);
                acc[i][j] = __builtin_amdgcn_mfma_f32_16x16x32_bf16(fa[i][1], fb[j][1], acc[i][j], 0, 0, 0);
            }
        __syncthreads();
    }

    if (rawOut) {   // exact integer partial sums in fp32
        #pragma unroll
        for (int i = 0; i < 4; ++i)
            #pragma unroll
            for (int j = 0; j < 4; ++j)
                #pragma unroll
                for (int rr = 0; rr < 4; ++rr) {
                    int m = (int)bm + wr * 64 + i * 16 + qa * 4 + rr;
                    int n = (int)bn + wc * 64 + j * 16 + rA;
                    rawOut[(size_t)m * 2048 + n] = acc[i][j][rr];
                }
        return;
    }

    const double scale = sumW[0] * invDivW * extraScale;
    double hs = 0.0;
    #pragma unroll
    for (int i = 0; i < 4; ++i) {
        #pragma unroll
        for (int j = 0; j < 4; ++j) {
            #pragma unroll
            for (int rr = 0; rr < 4; ++rr) {
                // C/D layout: col = lane&15, row = (lane>>4)*4 + reg
                int m = (int)bm + wr * 64 + i * 16 + qa * 4 + rr;
                int n = (int)bn + wc * 64 + j * 16 + rA;
                size_t idx = (size_t)m * 2048 + n;
                double s = (double)acc[i][j][rr];
                if (addPlane) s += (double)addPlane[idx];
                double z = s * scale + (n < 2000 ? (double)bias[n] : -1.0);
                binOut[idx] = (int8_t)(z > 0.0 ? 1 : 0);
                if (n < 2000 && z > 0.0) hs += z;
            }
        }
    }
    if (habs) block_reduce_atomic_d(hs, habs);
}

// i8 GEMM C = A @ B^T, A:[8192][2048] {0,1}, B:[2048][2048] {+-1,0}.
// 128x128 tile, BK=128, XOR-swizzled 16B chunks.
__global__ __launch_bounds__(256, 4) void gemm_i8(
    const int8_t* __restrict__ A, const int8_t* __restrict__ B,
    const double* __restrict__ sumW, double invDivW,
    const double* __restrict__ sumH, double invDivH,
    const float* __restrict__ bias,
    int8_t* __restrict__ binOut, bf16_t* __restrict__ hOut,
    double* __restrict__ habs)
{
    const int K = 2048;                           // bytes per row
    __shared__ __align__(16) int8_t sA[128 * 128];
    __shared__ __align__(16) int8_t sB[128 * 128];
    const int t = threadIdx.x;
    const int lane = t & 63;
    const int wave = t >> 6;
    const int wr = wave >> 1, wc = wave & 1;
    const int qa = lane >> 4, rA = lane & 15;
    const size_t bm = (size_t)blockIdx.y * 128, bn = (size_t)blockIdx.x * 128;

    i32x4 acc[4][4] = {};

    const int8_t* Abase = A + bm * (size_t)K;
    const int8_t* Bbase = B + bn * (size_t)K;

    const int swz = rA & 7;
    const int offb0 = ((0 + qa) ^ swz) * 16;      // k-half 0: k in [0,64)
    const int offb1 = ((4 + qa) ^ swz) * 16;      // k-half 1: k in [64,128)
    const int arow = wr * 64 + rA;
    const int brow = wc * 64 + rA;

    for (int k0 = 0; k0 < K; k0 += 128) {
        #pragma unroll
        for (int i = 0; i < 4; ++i) {
            int c = i * 256 + t;
            int row = c >> 3, cc = c & 7;
            int ccg = cc ^ (row & 7);
            GLD_LDS16(Abase + (size_t)row * K + k0 + ccg * 16, &sA[c * 16]);
        }
        #pragma unroll
        for (int i = 0; i < 4; ++i) {
            int c = i * 256 + t;
            int row = c >> 3, cc = c & 7;
            int ccg = cc ^ (row & 7);
            GLD_LDS16(Bbase + (size_t)row * K + k0 + ccg * 16, &sB[c * 16]);
        }
        __syncthreads();

        {   // k-half 0
            i32x4 fa[4], fb[4];
            #pragma unroll
            for (int i = 0; i < 4; ++i) {
                fa[i] = *(const i32x4*)&sA[(arow + i * 16) * 128 + offb0];
                fb[i] = *(const i32x4*)&sB[(brow + i * 16) * 128 + offb0];
            }
            #pragma unroll
            for (int i = 0; i < 4; ++i)
                #pragma unroll
                for (int j = 0; j < 4; ++j)
                    acc[i][j] = __builtin_amdgcn_mfma_i32_16x16x64_i8(fa[i], fb[j], acc[i][j], 0, 0, 0);
        }
        {   // k-half 1
            i32x4 fa[4], fb[4];
            #pragma unroll
            for (int i = 0; i < 4; ++i) {
                fa[i] = *(const i32x4*)&sA[(arow + i * 16) * 128 + offb1];
                fb[i] = *(const i32x4*)&sB[(brow + i * 16) * 128 + offb1];
            }
            #pragma unroll
            for (int i = 0; i < 4; ++i)
                #pragma unroll
                for (int j = 0; j < 4; ++j)
                    acc[i][j] = __builtin_amdgcn_mfma_i32_16x16x64_i8(fa[i], fb[j], acc[i][j], 0, 0, 0);
        }
        __syncthreads();
    }

    const double scale = sumW[0] * invDivW * sumH[0] * invDivH;
    double hs = 0.0;
    #pragma unroll
    for (int i = 0; i < 4; ++i) {
        #pragma unroll
        for (int j = 0; j < 4; ++j) {
            #pragma unroll
            for (int rr = 0; rr < 4; ++rr) {
                int m = (int)bm + wr * 64 + i * 16 + qa * 4 + rr;
                int n = (int)bn + wc * 64 + j * 16 + rA;
                size_t idx = (size_t)m * 2048 + n;
                double z = (double)acc[i][j][rr] * scale +
                           (n < 2000 ? (double)bias[n] : -1.0);
                if (binOut) binOut[idx] = (int8_t)(z > 0.0 ? 1 : 0);
                if (hOut)   hOut[idx] = (bf16_t)(float)(z > 0.0 ? z : 0.0);
                if (n < 2000 && z > 0.0) hs += z;
            }
        }
    }
    if (habs) block_reduce_atomic_d(hs, habs);
}

// out[8192][10] = h4[:, :2000] @ W5.T + b5  (h4 bf16, memory-bound)
__global__ __launch_bounds__(256) void fc_final(
    const bf16_t* __restrict__ h4, const float* __restrict__ W5,
    const float* __restrict__ b5, float* __restrict__ out)
{
    const int r = blockIdx.x, t = threadIdx.x;
    float acc[10] = {};
    for (int k = t; k < 2000; k += 256) {
        float a = (float)h4[(size_t)r * 2048 + k];
        #pragma unroll
        for (int c = 0; c < 10; ++c) acc[c] += a * W5[c * 2000 + k];
    }
    __shared__ float red[4][10];
    #pragma unroll
    for (int c = 0; c < 10; ++c) {
        float v = acc[c];
        #pragma unroll
        for (int off = 32; off > 0; off >>= 1) v += __shfl_down(v, off);
        if ((t & 63) == 0) red[t >> 6][c] = v;
    }
    __syncthreads();
    if (t < 10) out[(size_t)r * 10 + t] = red[0][t] + red[1][t] + red[2][t] + red[3][t] + b5[t];
}

extern "C" void kernel_launch(void* const* d_in, const int* in_sizes, int n_in,
                              void* d_out, int out_size, void* d_ws, size_t ws_size,
                              hipStream_t stream)
{
    const float* x  = (const float*)d_in[0];
    const float* W1 = (const float*)d_in[1];
    const float* b1 = (const float*)d_in[2];
    const float* W2 = (const float*)d_in[3];
    const float* b2 = (const float*)d_in[4];
    const float* W3 = (const float*)d_in[5];
    const float* b3 = (const float*)d_in[6];
    const float* W4 = (const float*)d_in[7];
    const float* b4 = (const float*)d_in[8];
    const float* W5 = (const float*)d_in[9];
    const float* b5 = (const float*)d_in[10];
    float* out = (float*)d_out;
    (void)ws_size; (void)in_sizes; (void)n_in; (void)out_size;

    const size_t PH = (size_t)8192 * 2048;

    // Workspace: R6 layout (260.3 MiB; 264 proven safe). sW1 = [s|s] dup again.
    char* w = (char*)d_ws;
    double* scD = (double*)w;                     // [0..3]=sum|W1..4|, [4..6]=sum h1..3
    size_t off = 256;
    bf16_t* XLi = (bf16_t*)(w + off); off += (size_t)8192 * 6144 * 2;  // 96 MiB
    bf16_t* XLr = (bf16_t*)(w + off); off += (size_t)8192 * 3072 * 2;  // 48 MiB
    bf16_t* sW1 = (bf16_t*)(w + off); off += (size_t)2048 * 6144 * 2;  // 24 MiB [s|s]
    float*  Ti  = (float*)(w + off);  off += PH * 4;                   // 64 MiB
    int8_t* p0  = (int8_t*)(w + off); off += PH;                       // 16 MiB
    int8_t* sW2 = (int8_t*)(w + off); off += (size_t)2048 * 2048;      // 4 MiB
    int8_t* sW3 = (int8_t*)(w + off); off += (size_t)2048 * 2048;      // 4 MiB
    int8_t* sW4 = (int8_t*)(w + off); off += (size_t)2048 * 2048;      // 4 MiB
    int8_t* p1  = (int8_t*)XLi;                    // XLi dead after L1 GEMMs
    bf16_t* h4  = (bf16_t*)Ti;                     // Ti dead after L1b epilogue

    hipMemsetAsync(w, 0, 256, stream);
    // one fused prep dispatch: W1 signs (bf16 [s|s]), W2-4 signs (i8), x limbs
    prep_all<<<16384, 256, 0, stream>>>(W1, W2, W3, W4, x,
                                        sW1, sW2, sW3, sW4, XLi, XLr, scD);

    // L1a (R13): 8-phase 256x256 schedule, Ti = [hi|lo] @ [s|s]^T exact
    gemm_l1a8<<<256, 512, 0, stream>>>(XLi, sW1, Ti);

    dim3 grid(16, 64), blk(256);
    // L1b: residual GEMM + fused combine (PROVEN R6 form, ldB=6144)
    gemm_bin<<<grid, blk, 0, stream>>>(XLr, sW1, 3072, 6144, nullptr, Ti,
                                       scD + 0, 1.0 / 6144000.0, 1.0 / 16384.0,
                                       b1, p0, scD + 4);

    // Layers 2-4: exact i8 GEMMs, double epilogue
    gemm_i8<<<grid, blk, 0, stream>>>(p0, sW2,
                                      scD + 1, 1.0 / 4000000.0, scD + 4, 1.0 / 16384000.0,
                                      b2, p1, nullptr, scD + 5);
    gemm_i8<<<grid, blk, 0, stream>>>(p1, sW3,
                                      scD + 2, 1.0 / 4000000.0, scD + 5, 1.0 / 16384000.0,
                                      b3, p0, nullptr, scD + 6);
    gemm_i8<<<grid, blk, 0, stream>>>(p0, sW4,
                                      scD + 3, 1.0 / 4000000.0, scD + 6, 1.0 / 16384000.0,
                                      b4, nullptr, h4, nullptr);
    fc_final<<<8192, 256, 0, stream>>>(h4, W5, b5, out);
}